// Round 15
// baseline (149.280 us; speedup 1.0000x reference)
//
#include <hip/hip_runtime.h>
#include <hip/hip_fp16.h>
#include <math.h>

// Problem constants
#define HID   1024
#define NHEAD 16
#define HD    64
#define NB    64
#define MAXS  2048
#define CHUNK 256
#define NCH   (MAXS / CHUNK)          // 8
#define PS    68                      // floats per (chunk,b,h) partial record
#define NKS   16                      // proj k-slices

// Non-temporal loads: stream-once data (KV cache, W matrices).
typedef float f4v __attribute__((ext_vector_type(4)));
typedef float f2v __attribute__((ext_vector_type(2)));
__device__ __forceinline__ float4 ntload4(const float* p) {
    f4v v = __builtin_nontemporal_load((const f4v*)p);
    return make_float4(v.x, v.y, v.z, v.w);
}
__device__ __forceinline__ float2 ntload2(const float* p) {
    f2v v = __builtin_nontemporal_load((const f2v*)p);
    return make_float2(v.x, v.y);
}

// ---------------------------------------------------------------------------
// Kernel 1a: projection partials, lane=2-COLUMNS (Tc=2 register blocking).
// R12/R14 invariant: 1 broadcast ds_read_b128 per 4 FMAs -> LDS-throughput
// wall (~12 cyc/b128) -> proj pinned at ~30us. Fix: each lane owns TWO
// columns, so one s-broadcast b128 (4 k) feeds 8 FMAs -> LDS instr count
// halves, VALU becomes the binding pipe. W preloaded per-lane as float2
// (512 B/wave-instr, nt). Block = (cg: 128 cols, kb: 64 k) x 4 waves
// (wave wv owns 16 k-rows); sequential in-block LDS reduce (R14-verified);
// partial[16][64][4096] unchanged -> proj2 identical.
// ---------------------------------------------------------------------------
__global__ __launch_bounds__(256) void proj1_kernel(
    const float* __restrict__ seq, const float* __restrict__ cand,
    const float* __restrict__ Wqkv, const float* __restrict__ Wc,
    float* __restrict__ partial /* [NKS][64][4096] */)
{
    const int tid  = threadIdx.x;
    const int wv   = tid >> 6;
    const int lane = tid & 63;
    const int bid  = blockIdx.x;
    const int cg   = bid & 31;                 // col-group (128 cols) 0..31
    const int kb   = bid >> 5;                 // k-block (64 k) 0..15
    const int k0   = kb * 64;
    const bool is_qkv = (cg < 24);             // col 3072 boundary = cg 24
    const float* __restrict__ src = is_qkv ? seq  : cand;
    const float* __restrict__ W   = is_qkv ? Wqkv : Wc;
    const int ldw = is_qkv ? 3072 : 1024;
    const int c0  = (is_qkv ? cg * 128 : (cg - 24) * 128);   // W col base
    const int gc0 = cg * 128;                  // output col base

    __shared__ float s_lds[64][68];            // 17.4 KB staged s slice [b][k]
    __shared__ float red[64][132];             // 33.8 KB reduce buffer (16B-aligned rows)

    // ---- stage s slice [64 b][64 k]: coalesced float4 per thread ----
    {
        const int b = tid >> 2, q = tid & 3;
        const float* sb = src + b * HID + k0;
        #pragma unroll
        for (int i = 0; i < 4; ++i) {
            const int kk = (q + i * 4) * 4;
            *(float4*)&s_lds[b][kk] = *(const float4*)(sb + kk);
        }
    }
    __syncthreads();

    // ---- preload this wave's 16 W rows x 2 cols (coalesced float2, nt) ----
    const int kw = wv * 16;
    float2 w2[16];
    const float* wp = W + (size_t)(k0 + kw) * ldw + c0 + lane * 2;
    #pragma unroll
    for (int i = 0; i < 16; ++i) w2[i] = ntload2(wp + (size_t)i * ldw);

    // ---- accumulate: 64 batches x 2 cols; 1 b128 broadcast -> 8 FMAs ----
    float2 acc[64];
    #pragma unroll
    for (int b = 0; b < 64; ++b) acc[b] = make_float2(0.f, 0.f);

    #pragma unroll
    for (int kq = 0; kq < 4; ++kq) {
        #pragma unroll
        for (int b = 0; b < 64; ++b) {
            float4 s4 = *(const float4*)&s_lds[b][kw + kq * 4];   // broadcast
            acc[b].x = fmaf(s4.x, w2[kq*4+0].x, fmaf(s4.y, w2[kq*4+1].x,
                       fmaf(s4.z, w2[kq*4+2].x, fmaf(s4.w, w2[kq*4+3].x, acc[b].x))));
            acc[b].y = fmaf(s4.x, w2[kq*4+0].y, fmaf(s4.y, w2[kq*4+1].y,
                       fmaf(s4.z, w2[kq*4+2].y, fmaf(s4.w, w2[kq*4+3].y, acc[b].y))));
        }
    }
    __syncthreads();                           // all waves done reading s_lds

    // ---- sequential 4-wave reduce into red[b][128] (R14-verified pattern) ----
    if (wv == 0) {
        #pragma unroll
        for (int b = 0; b < 64; ++b) *(float2*)&red[b][lane * 2] = acc[b];
    }
    __syncthreads();
    if (wv == 1) {
        #pragma unroll
        for (int b = 0; b < 64; ++b) {
            float2 r = *(const float2*)&red[b][lane * 2];
            r.x += acc[b].x; r.y += acc[b].y;
            *(float2*)&red[b][lane * 2] = r;
        }
    }
    __syncthreads();
    if (wv == 2) {
        #pragma unroll
        for (int b = 0; b < 64; ++b) {
            float2 r = *(const float2*)&red[b][lane * 2];
            r.x += acc[b].x; r.y += acc[b].y;
            *(float2*)&red[b][lane * 2] = r;
        }
    }
    __syncthreads();
    if (wv == 3) {
        #pragma unroll
        for (int b = 0; b < 64; ++b) {
            float2 r = *(const float2*)&red[b][lane * 2];
            r.x += acc[b].x; r.y += acc[b].y;
            *(float2*)&red[b][lane * 2] = r;
        }
    }
    __syncthreads();

    // ---- write partial[kb][b][gc0..gc0+127]: thread t -> b = t>>2, q = t&3 ----
    {
        const int b = tid >> 2, q = tid & 3;
        float* pb = partial + (size_t)(kb * 64 + b) * 4096 + gc0;
        #pragma unroll
        for (int i = 0; i < 8; ++i) {
            const int c = (q + i * 4) * 4;     // 16B-aligned (red rows 528 B)
            *(float4*)(pb + c) = *(const float4*)&red[b][c];
        }
    }
}

// ---------------------------------------------------------------------------
// Kernel 1b: reduce 16 k-slice partials + bias -> proj ROW-MAJOR [64][4096].
// ---------------------------------------------------------------------------
__global__ __launch_bounds__(1024) void proj2_kernel(
    const float* __restrict__ partial, const float* __restrict__ bqkv,
    const float* __restrict__ bcv, float* __restrict__ projRM /* [64][4096] */)
{
    const int T   = blockIdx.x * 1024 + threadIdx.x;
    const int b   = T >> 12;
    const int col = T & 4095;
    float v = (col < 3072) ? bqkv[col] : bcv[col - 3072];
    #pragma unroll
    for (int ks = 0; ks < NKS; ++ks)
        v += partial[(size_t)(ks * 64 + b) * 4096 + col];
    projRM[(size_t)b * 4096 + col] = v;
}

// ---------------------------------------------------------------------------
// Kernel 2: TWO-PHASE chunked attention partials, nt loads (R8 structure,
// measured 6.4 TB/s = read roofline). Row-major proj reads (verified).
// ---------------------------------------------------------------------------
__global__ __launch_bounds__(256) void attn_part_kernel(
    const float* __restrict__ projRM, const float* __restrict__ k_cache,
    const float* __restrict__ v_cache, const int* __restrict__ seqlens,
    float* __restrict__ part)
{
    const int idx = blockIdx.x;
    const int c  = idx >> 10;
    const int bh = idx & 1023;
    const int b  = bh >> 4;
    const int h  = bh & 15;
    const int L  = seqlens[b];
    const int s0 = c << 8;
    if (s0 > L) return;

    const int tid = threadIdx.x;
    const int grp = tid >> 4;
    const int gl  = tid & 15;
    const bool has_new = (L < s0 + CHUNK);
    const float* prow = projRM + (size_t)b * 4096 + h * 192;

    __shared__ float lq[64], lk[64], lv[64];
    __shared__ float sm_m[16], sm_l[16];
    __shared__ float sm_o[16][64];

    if (tid < 64) {
        lq[tid] = prow[tid];
    } else if (tid < 128) {
        if (has_new) {
            int d = tid - 64;
            float kr = prow[64 + d];
            float ss = kr * kr;
            #pragma unroll
            for (int m = 1; m < 64; m <<= 1) ss += __shfl_xor(ss, m);
            float kn = kr / sqrtf(ss);
            lk[d] = __half2float(__float2half_rn(kn));
        }
    } else if (tid < 192) {
        if (has_new) {
            int d = tid - 128;
            lv[d] = prow[128 + d];
        }
    }
    __syncthreads();

    const float4 q4 = ((const float4*)lq)[gl];
    const size_t base0 = (((size_t)b * MAXS) * NHEAD + h) * HD;

    float sc[16];
    float m, l;
    float4 o = make_float4(0.f, 0.f, 0.f, 0.f);

    if (!has_new) {
        #pragma unroll
        for (int t = 0; t < 16; ++t) {
            const int s = s0 + grp + t * 16;
            float4 k4 = ntload4(k_cache + base0 + (size_t)s * (NHEAD * HD) + gl * 4);
            float d = fmaf(k4.x, q4.x, fmaf(k4.y, q4.y, fmaf(k4.z, q4.z, k4.w * q4.w)));
            d += __shfl_xor(d, 1); d += __shfl_xor(d, 2);
            d += __shfl_xor(d, 4); d += __shfl_xor(d, 8);
            sc[t] = d;
        }
        m = sc[0];
        #pragma unroll
        for (int t = 1; t < 16; ++t) m = fmaxf(m, sc[t]);
        l = 0.f;
        #pragma unroll
        for (int t = 0; t < 16; ++t) { float p = __expf(sc[t] - m); sc[t] = p; l += p; }
        #pragma unroll
        for (int t = 0; t < 16; ++t) {
            const int s = s0 + grp + t * 16;
            float4 v4 = ntload4(v_cache + base0 + (size_t)s * (NHEAD * HD) + gl * 4);
            o.x = fmaf(sc[t], v4.x, o.x);
            o.y = fmaf(sc[t], v4.y, o.y);
            o.z = fmaf(sc[t], v4.z, o.z);
            o.w = fmaf(sc[t], v4.w, o.w);
        }
    } else {
        #pragma unroll
        for (int t = 0; t < 16; ++t) {
            const int s = s0 + grp + t * 16;
            float4 k4 = make_float4(0.f, 0.f, 0.f, 0.f);
            if (s < L)       k4 = ntload4(k_cache + base0 + (size_t)s * (NHEAD * HD) + gl * 4);
            else if (s == L) k4 = ((const float4*)lk)[gl];
            float d = fmaf(k4.x, q4.x, fmaf(k4.y, q4.y, fmaf(k4.z, q4.z, k4.w * q4.w)));
            d += __shfl_xor(d, 1); d += __shfl_xor(d, 2);
            d += __shfl_xor(d, 4); d += __shfl_xor(d, 8);
            sc[t] = (s <= L) ? d : -INFINITY;
        }
        m = sc[0];
        #pragma unroll
        for (int t = 1; t < 16; ++t) m = fmaxf(m, sc[t]);
        const float mm = (m == -INFINITY) ? 0.f : m;   // NaN guard (empty group)
        l = 0.f;
        #pragma unroll
        for (int t = 0; t < 16; ++t) { float p = __expf(sc[t] - mm); sc[t] = p; l += p; }
        #pragma unroll
        for (int t = 0; t < 16; ++t) {
            const int s = s0 + grp + t * 16;
            float4 v4 = make_float4(0.f, 0.f, 0.f, 0.f);
            if (s < L)       v4 = ntload4(v_cache + base0 + (size_t)s * (NHEAD * HD) + gl * 4);
            else if (s == L) v4 = ((const float4*)lv)[gl];
            o.x = fmaf(sc[t], v4.x, o.x);
            o.y = fmaf(sc[t], v4.y, o.y);
            o.z = fmaf(sc[t], v4.z, o.z);
            o.w = fmaf(sc[t], v4.w, o.w);
        }
    }

    if (gl == 0) { sm_m[grp] = m; sm_l[grp] = l; }
    ((float4*)sm_o[grp])[gl] = o;
    __syncthreads();

    if (tid < 64) {
        float M = -INFINITY;
        #pragma unroll
        for (int g = 0; g < 16; ++g) M = fmaxf(M, sm_m[g]);
        float li = 0.f, oi = 0.f;
        #pragma unroll
        for (int g = 0; g < 16; ++g) {
            float w = __expf(sm_m[g] - M);
            li += w * sm_l[g];
            oi += w * sm_o[g][tid];
        }
        float* pb = part + (size_t)(c * 1024 + bh) * PS;
        pb[tid] = oi;
        if (tid == 0) { pb[64] = M; pb[65] = li; }
    }
}

// ---------------------------------------------------------------------------
// Kernel 3: merge <=8 chunk partials per (b,h). 1024 blocks x 64 threads.
// ---------------------------------------------------------------------------
__global__ __launch_bounds__(64) void attn_merge_kernel(
    const float* __restrict__ part, const int* __restrict__ seqlens,
    float* __restrict__ attn_out /* [1024][64] col-major */)
{
    const int bh = blockIdx.x;
    const int b  = bh >> 4;
    const int h  = bh & 15;
    const int d  = threadIdx.x;
    const int nch = (seqlens[b] >> 8) + 1;

    float M = -INFINITY, l = 0.f, o = 0.f;
    for (int c = 0; c < nch; ++c) {
        const float* pb = part + (size_t)(c * 1024 + bh) * PS;
        float mc = pb[64], lc = pb[65];
        float Mn = fmaxf(M, mc);
        float f = __expf(M - Mn);
        float w = __expf(mc - Mn);
        o = o * f + w * pb[d];
        l = l * f + w * lc;
        M = Mn;
    }
    attn_out[(h * 64 + d) * 64 + b] = o / l;
}

// ---------------------------------------------------------------------------
// Kernel 4: postx = attn @ Wo + bo (unchanged — Wo read exactly once)
// ---------------------------------------------------------------------------
__global__ __launch_bounds__(1024) void wo_kernel(
    const float* __restrict__ attn_s, const float* __restrict__ Wo,
    const float* __restrict__ bo, float* __restrict__ postx /* [1024][64] */)
{
    const int tid  = threadIdx.x;
    const int wv   = __builtin_amdgcn_readfirstlane(tid >> 6);
    const int lane = tid & 63;
    const int c0   = blockIdx.x * 8;
    const int k0   = wv * 64;

    float acc[8];
    #pragma unroll
    for (int j = 0; j < 8; ++j) acc[j] = 0.f;

    for (int k = 0; k < 64; ++k) {
        float sv = attn_s[(k0 + k) * 64 + lane];
        const float4* wr = (const float4*)(Wo + (size_t)(k0 + k) * 1024 + c0);
        float4 w0 = wr[0], w1 = wr[1];
        acc[0] = fmaf(sv, w0.x, acc[0]); acc[1] = fmaf(sv, w0.y, acc[1]);
        acc[2] = fmaf(sv, w0.z, acc[2]); acc[3] = fmaf(sv, w0.w, acc[3]);
        acc[4] = fmaf(sv, w1.x, acc[4]); acc[5] = fmaf(sv, w1.y, acc[5]);
        acc[6] = fmaf(sv, w1.z, acc[6]); acc[7] = fmaf(sv, w1.w, acc[7]);
    }

    __shared__ float red[16][8][64];
    #pragma unroll
    for (int j = 0; j < 8; ++j) red[wv][j][lane] = acc[j];
    __syncthreads();

    if (tid < 512) {
        const int j = tid >> 6, b = tid & 63;
        float s = 0.f;
        #pragma unroll
        for (int w = 0; w < 16; ++w) s += red[w][j][b];
        postx[(c0 + j) * 64 + b] = s + bo[c0 + j];
    }
}

// ---------------------------------------------------------------------------
// Kernel 5: dual LayerNorm (row-major proj reads, verified)
// ---------------------------------------------------------------------------
__global__ __launch_bounds__(256) void ln_kernel(
    const float* __restrict__ seq, const float* __restrict__ projRM,
    const float* __restrict__ postx, const float* __restrict__ gamma,
    const float* __restrict__ beta, float* __restrict__ out)
{
    const int b   = blockIdx.x;
    const int tid = threadIdx.x;
    float x1[4], x2[4];
    float s1 = 0.f, q1 = 0.f, s2 = 0.f, q2 = 0.f;

    #pragma unroll
    for (int i = 0; i < 4; ++i) {
        int c = tid + i * 256;
        float px = postx[c * 64 + b];
        float sv = seq[b * HID + c];
        float cd = projRM[(size_t)b * 4096 + 3072 + c];
        float a = sv + px, d = px + cd;
        x1[i] = a; x2[i] = d;
        s1 += a; q1 += a * a; s2 += d; q2 += d * d;
    }
    #pragma unroll
    for (int m = 1; m < 64; m <<= 1) {
        s1 += __shfl_xor(s1, m); q1 += __shfl_xor(q1, m);
        s2 += __shfl_xor(s2, m); q2 += __shfl_xor(q2, m);
    }
    __shared__ float rsm[4][4];
    const int wv = tid >> 6, lane = tid & 63;
    if (lane == 0) { rsm[wv][0] = s1; rsm[wv][1] = q1; rsm[wv][2] = s2; rsm[wv][3] = q2; }
    __syncthreads();

    float S1 = rsm[0][0] + rsm[1][0] + rsm[2][0] + rsm[3][0];
    float Q1 = rsm[0][1] + rsm[1][1] + rsm[2][1] + rsm[3][1];
    float S2 = rsm[0][2] + rsm[1][2] + rsm[2][2] + rsm[3][2];
    float Q2 = rsm[0][3] + rsm[1][3] + rsm[2][3] + rsm[3][3];

    const float inv = 1.f / 1024.f;
    float mu1 = S1 * inv, v1 = Q1 * inv - mu1 * mu1;
    float mu2 = S2 * inv, v2 = Q2 * inv - mu2 * mu2;
    float r1 = rsqrtf(v1 + 1e-5f);
    float r2 = rsqrtf(v2 + 1e-5f);

    #pragma unroll
    for (int i = 0; i < 4; ++i) {
        int c = tid + i * 256;
        float g = gamma[c], be = beta[c];
        out[b * HID + c]            = (x1[i] - mu1) * r1 * g + be;   // seq_out
        out[NB * HID + b * HID + c] = (x2[i] - mu2) * r2 * g + be;   // candidate_out
    }
}

// ---------------------------------------------------------------------------
extern "C" void kernel_launch(void* const* d_in, const int* in_sizes, int n_in,
                              void* d_out, int out_size, void* d_ws, size_t ws_size,
                              hipStream_t stream) {
    const float* seq      = (const float*)d_in[0];
    const float* cand     = (const float*)d_in[1];
    const float* k_cache  = (const float*)d_in[2];
    const float* v_cache  = (const float*)d_in[3];
    const int*   seqlens  = (const int*)  d_in[4];
    const float* Wqkv     = (const float*)d_in[5];
    const float* bqkv     = (const float*)d_in[6];
    const float* Wc       = (const float*)d_in[7];
    const float* bcv      = (const float*)d_in[8];
    const float* Wo       = (const float*)d_in[9];
    const float* bo       = (const float*)d_in[10];
    const float* gamma    = (const float*)d_in[11];
    const float* beta     = (const float*)d_in[12];
    float* out = (float*)d_out;

    float* ws      = (float*)d_ws;
    float* projRM  = ws;                          // [64][4096]      = 262144 f
    float* attn    = projRM + 64 * 4096;          // [1024][64]      =  65536 f
    float* postx   = attn   + 1024 * 64;          // [1024][64]      =  65536 f
    float* part    = postx  + 1024 * 64;          // [8*1024][PS]    = 557056 f
    float* partial = part   + NCH * 1024 * PS;    // [16][64][4096]  = 4194304 f (16 MB)

    proj1_kernel     <<<512, 256, 0, stream>>>(seq, cand, Wqkv, Wc, partial);
    proj2_kernel     <<<256, 1024, 0, stream>>>(partial, bqkv, bcv, projRM);
    attn_part_kernel <<<NCH * 1024, 256, 0, stream>>>(projRM, k_cache, v_cache, seqlens, part);
    attn_merge_kernel<<<NB * NHEAD, 64, 0, stream>>>(part, seqlens, attn);
    wo_kernel        <<<128, 1024, 0, stream>>>(attn, Wo, bo, postx);
    ln_kernel        <<<NB, 256, 0, stream>>>(seq, projRM, postx, gamma, beta, out);
}

// Round 16
// 136.195 us; speedup vs baseline: 1.0961x; 1.0961x over previous
//
#include <hip/hip_runtime.h>
#include <hip/hip_fp16.h>
#include <math.h>

// Problem constants
#define HID   1024
#define NHEAD 16
#define HD    64
#define NB    64
#define MAXS  2048
#define CHUNK 256
#define NCH   (MAXS / CHUNK)          // 8
#define PS    68                      // floats per (chunk,b,h) partial record
#define NKS   16                      // proj k-slices

// Non-temporal loads: stream-once data (KV cache, W matrices).
typedef float f4v __attribute__((ext_vector_type(4)));
typedef float f2v __attribute__((ext_vector_type(2)));
__device__ __forceinline__ float4 ntload4(const float* p) {
    f4v v = __builtin_nontemporal_load((const f4v*)p);
    return make_float4(v.x, v.y, v.z, v.w);
}
__device__ __forceinline__ float2 ntload2(const float* p) {
    f2v v = __builtin_nontemporal_load((const f2v*)p);
    return make_float2(v.x, v.y);
}

// ---------------------------------------------------------------------------
// Kernel 1a: projection partials, Tc=2, TWO BATCH-PASSES (VGPR <= ~115).
// Mechanism model (closed in R14/R15): proj is LDS-broadcast-bound —
// ds_read_b128 costs ~12 cyc even for uniform addresses; R14 = 16 waves/CU
// x 256 reads = ~20us. Tc=2 halves reads per output, but R15's float2
// acc[64] (128 VGPR + 32 w2) hit a register cliff/spill (+12us). Fix: two
// passes over batches with float2 acc[32] (64 VGPR); LDS/CU now 8 waves x
// 256 b128 ~ 10us. Math/indexing otherwise identical to R15 (verified).
// ---------------------------------------------------------------------------
__global__ __launch_bounds__(256) void proj1_kernel(
    const float* __restrict__ seq, const float* __restrict__ cand,
    const float* __restrict__ Wqkv, const float* __restrict__ Wc,
    float* __restrict__ partial /* [NKS][64][4096] */)
{
    const int tid  = threadIdx.x;
    const int wv   = tid >> 6;
    const int lane = tid & 63;
    const int bid  = blockIdx.x;
    const int cg   = bid & 31;                 // col-group (128 cols) 0..31
    const int kb   = bid >> 5;                 // k-block (64 k) 0..15
    const int k0   = kb * 64;
    const bool is_qkv = (cg < 24);             // col 3072 boundary = cg 24
    const float* __restrict__ src = is_qkv ? seq  : cand;
    const float* __restrict__ W   = is_qkv ? Wqkv : Wc;
    const int ldw = is_qkv ? 3072 : 1024;
    const int c0  = (is_qkv ? cg * 128 : (cg - 24) * 128);   // W col base
    const int gc0 = cg * 128;                  // output col base

    __shared__ float s_lds[64][68];            // 17.4 KB staged s slice [b][k]
    __shared__ float red[32][132];             // 16.9 KB reduce buffer (per pass)

    // ---- stage s slice [64 b][64 k]: coalesced float4 per thread ----
    {
        const int b = tid >> 2, q = tid & 3;
        const float* sb = src + b * HID + k0;
        #pragma unroll
        for (int i = 0; i < 4; ++i) {
            const int kk = (q + i * 4) * 4;
            *(float4*)&s_lds[b][kk] = *(const float4*)(sb + kk);
        }
    }

    // ---- preload this wave's 16 W rows x 2 cols (coalesced float2, nt) ----
    const int kw = wv * 16;
    float2 w2[16];
    const float* wp = W + (size_t)(k0 + kw) * ldw + c0 + lane * 2;
    #pragma unroll
    for (int i = 0; i < 16; ++i) w2[i] = ntload2(wp + (size_t)i * ldw);
    __syncthreads();                           // s_lds ready

    // ---- two passes over batch halves: acc float2[32] (64 VGPR) ----
    for (int pass = 0; pass < 2; ++pass) {
        const int b0 = pass * 32;
        float2 acc[32];
        #pragma unroll
        for (int rb = 0; rb < 32; ++rb) acc[rb] = make_float2(0.f, 0.f);

        #pragma unroll
        for (int kq = 0; kq < 4; ++kq) {
            #pragma unroll
            for (int rb = 0; rb < 32; ++rb) {
                float4 s4 = *(const float4*)&s_lds[b0 + rb][kw + kq * 4];  // broadcast
                acc[rb].x = fmaf(s4.x, w2[kq*4+0].x, fmaf(s4.y, w2[kq*4+1].x,
                            fmaf(s4.z, w2[kq*4+2].x, fmaf(s4.w, w2[kq*4+3].x, acc[rb].x))));
                acc[rb].y = fmaf(s4.x, w2[kq*4+0].y, fmaf(s4.y, w2[kq*4+1].y,
                            fmaf(s4.z, w2[kq*4+2].y, fmaf(s4.w, w2[kq*4+3].y, acc[rb].y))));
            }
        }

        // ---- sequential 4-wave reduce into red[rb][128] (R15-verified) ----
        if (wv == 0) {
            #pragma unroll
            for (int rb = 0; rb < 32; ++rb) *(float2*)&red[rb][lane * 2] = acc[rb];
        }
        __syncthreads();
        if (wv == 1) {
            #pragma unroll
            for (int rb = 0; rb < 32; ++rb) {
                float2 r = *(const float2*)&red[rb][lane * 2];
                r.x += acc[rb].x; r.y += acc[rb].y;
                *(float2*)&red[rb][lane * 2] = r;
            }
        }
        __syncthreads();
        if (wv == 2) {
            #pragma unroll
            for (int rb = 0; rb < 32; ++rb) {
                float2 r = *(const float2*)&red[rb][lane * 2];
                r.x += acc[rb].x; r.y += acc[rb].y;
                *(float2*)&red[rb][lane * 2] = r;
            }
        }
        __syncthreads();
        if (wv == 3) {
            #pragma unroll
            for (int rb = 0; rb < 32; ++rb) {
                float2 r = *(const float2*)&red[rb][lane * 2];
                r.x += acc[rb].x; r.y += acc[rb].y;
                *(float2*)&red[rb][lane * 2] = r;
            }
        }
        __syncthreads();

        // ---- write partial rows b0..b0+31: 8 threads/row, 4x float4 each ----
        {
            const int rb = tid >> 3, q = tid & 7;
            float* pb = partial + (size_t)(kb * 64 + b0 + rb) * 4096 + gc0 + q * 16;
            #pragma unroll
            for (int i = 0; i < 4; ++i)
                *(float4*)(pb + i * 4) = *(const float4*)&red[rb][q * 16 + i * 4];
        }
        __syncthreads();                       // red reused next pass
    }
}

// ---------------------------------------------------------------------------
// Kernel 1b: reduce 16 k-slice partials + bias -> proj ROW-MAJOR [64][4096].
// ---------------------------------------------------------------------------
__global__ __launch_bounds__(1024) void proj2_kernel(
    const float* __restrict__ partial, const float* __restrict__ bqkv,
    const float* __restrict__ bcv, float* __restrict__ projRM /* [64][4096] */)
{
    const int T   = blockIdx.x * 1024 + threadIdx.x;
    const int b   = T >> 12;
    const int col = T & 4095;
    float v = (col < 3072) ? bqkv[col] : bcv[col - 3072];
    #pragma unroll
    for (int ks = 0; ks < NKS; ++ks)
        v += partial[(size_t)(ks * 64 + b) * 4096 + col];
    projRM[(size_t)b * 4096 + col] = v;
}

// ---------------------------------------------------------------------------
// Kernel 2: TWO-PHASE chunked attention partials, nt loads (R8 structure,
// measured 6.4 TB/s = read roofline). Row-major proj reads (verified).
// ---------------------------------------------------------------------------
__global__ __launch_bounds__(256) void attn_part_kernel(
    const float* __restrict__ projRM, const float* __restrict__ k_cache,
    const float* __restrict__ v_cache, const int* __restrict__ seqlens,
    float* __restrict__ part)
{
    const int idx = blockIdx.x;
    const int c  = idx >> 10;
    const int bh = idx & 1023;
    const int b  = bh >> 4;
    const int h  = bh & 15;
    const int L  = seqlens[b];
    const int s0 = c << 8;
    if (s0 > L) return;

    const int tid = threadIdx.x;
    const int grp = tid >> 4;
    const int gl  = tid & 15;
    const bool has_new = (L < s0 + CHUNK);
    const float* prow = projRM + (size_t)b * 4096 + h * 192;

    __shared__ float lq[64], lk[64], lv[64];
    __shared__ float sm_m[16], sm_l[16];
    __shared__ float sm_o[16][64];

    if (tid < 64) {
        lq[tid] = prow[tid];
    } else if (tid < 128) {
        if (has_new) {
            int d = tid - 64;
            float kr = prow[64 + d];
            float ss = kr * kr;
            #pragma unroll
            for (int m = 1; m < 64; m <<= 1) ss += __shfl_xor(ss, m);
            float kn = kr / sqrtf(ss);
            lk[d] = __half2float(__float2half_rn(kn));
        }
    } else if (tid < 192) {
        if (has_new) {
            int d = tid - 128;
            lv[d] = prow[128 + d];
        }
    }
    __syncthreads();

    const float4 q4 = ((const float4*)lq)[gl];
    const size_t base0 = (((size_t)b * MAXS) * NHEAD + h) * HD;

    float sc[16];
    float m, l;
    float4 o = make_float4(0.f, 0.f, 0.f, 0.f);

    if (!has_new) {
        #pragma unroll
        for (int t = 0; t < 16; ++t) {
            const int s = s0 + grp + t * 16;
            float4 k4 = ntload4(k_cache + base0 + (size_t)s * (NHEAD * HD) + gl * 4);
            float d = fmaf(k4.x, q4.x, fmaf(k4.y, q4.y, fmaf(k4.z, q4.z, k4.w * q4.w)));
            d += __shfl_xor(d, 1); d += __shfl_xor(d, 2);
            d += __shfl_xor(d, 4); d += __shfl_xor(d, 8);
            sc[t] = d;
        }
        m = sc[0];
        #pragma unroll
        for (int t = 1; t < 16; ++t) m = fmaxf(m, sc[t]);
        l = 0.f;
        #pragma unroll
        for (int t = 0; t < 16; ++t) { float p = __expf(sc[t] - m); sc[t] = p; l += p; }
        #pragma unroll
        for (int t = 0; t < 16; ++t) {
            const int s = s0 + grp + t * 16;
            float4 v4 = ntload4(v_cache + base0 + (size_t)s * (NHEAD * HD) + gl * 4);
            o.x = fmaf(sc[t], v4.x, o.x);
            o.y = fmaf(sc[t], v4.y, o.y);
            o.z = fmaf(sc[t], v4.z, o.z);
            o.w = fmaf(sc[t], v4.w, o.w);
        }
    } else {
        #pragma unroll
        for (int t = 0; t < 16; ++t) {
            const int s = s0 + grp + t * 16;
            float4 k4 = make_float4(0.f, 0.f, 0.f, 0.f);
            if (s < L)       k4 = ntload4(k_cache + base0 + (size_t)s * (NHEAD * HD) + gl * 4);
            else if (s == L) k4 = ((const float4*)lk)[gl];
            float d = fmaf(k4.x, q4.x, fmaf(k4.y, q4.y, fmaf(k4.z, q4.z, k4.w * q4.w)));
            d += __shfl_xor(d, 1); d += __shfl_xor(d, 2);
            d += __shfl_xor(d, 4); d += __shfl_xor(d, 8);
            sc[t] = (s <= L) ? d : -INFINITY;
        }
        m = sc[0];
        #pragma unroll
        for (int t = 1; t < 16; ++t) m = fmaxf(m, sc[t]);
        const float mm = (m == -INFINITY) ? 0.f : m;   // NaN guard (empty group)
        l = 0.f;
        #pragma unroll
        for (int t = 0; t < 16; ++t) { float p = __expf(sc[t] - mm); sc[t] = p; l += p; }
        #pragma unroll
        for (int t = 0; t < 16; ++t) {
            const int s = s0 + grp + t * 16;
            float4 v4 = make_float4(0.f, 0.f, 0.f, 0.f);
            if (s < L)       v4 = ntload4(v_cache + base0 + (size_t)s * (NHEAD * HD) + gl * 4);
            else if (s == L) v4 = ((const float4*)lv)[gl];
            o.x = fmaf(sc[t], v4.x, o.x);
            o.y = fmaf(sc[t], v4.y, o.y);
            o.z = fmaf(sc[t], v4.z, o.z);
            o.w = fmaf(sc[t], v4.w, o.w);
        }
    }

    if (gl == 0) { sm_m[grp] = m; sm_l[grp] = l; }
    ((float4*)sm_o[grp])[gl] = o;
    __syncthreads();

    if (tid < 64) {
        float M = -INFINITY;
        #pragma unroll
        for (int g = 0; g < 16; ++g) M = fmaxf(M, sm_m[g]);
        float li = 0.f, oi = 0.f;
        #pragma unroll
        for (int g = 0; g < 16; ++g) {
            float w = __expf(sm_m[g] - M);
            li += w * sm_l[g];
            oi += w * sm_o[g][tid];
        }
        float* pb = part + (size_t)(c * 1024 + bh) * PS;
        pb[tid] = oi;
        if (tid == 0) { pb[64] = M; pb[65] = li; }
    }
}

// ---------------------------------------------------------------------------
// Kernel 3: merge <=8 chunk partials per (b,h). 1024 blocks x 64 threads.
// ---------------------------------------------------------------------------
__global__ __launch_bounds__(64) void attn_merge_kernel(
    const float* __restrict__ part, const int* __restrict__ seqlens,
    float* __restrict__ attn_out /* [1024][64] col-major */)
{
    const int bh = blockIdx.x;
    const int b  = bh >> 4;
    const int h  = bh & 15;
    const int d  = threadIdx.x;
    const int nch = (seqlens[b] >> 8) + 1;

    float M = -INFINITY, l = 0.f, o = 0.f;
    for (int c = 0; c < nch; ++c) {
        const float* pb = part + (size_t)(c * 1024 + bh) * PS;
        float mc = pb[64], lc = pb[65];
        float Mn = fmaxf(M, mc);
        float f = __expf(M - Mn);
        float w = __expf(mc - Mn);
        o = o * f + w * pb[d];
        l = l * f + w * lc;
        M = Mn;
    }
    attn_out[(h * 64 + d) * 64 + b] = o / l;
}

// ---------------------------------------------------------------------------
// Kernel 4: postx = attn @ Wo + bo (unchanged — Wo read exactly once)
// ---------------------------------------------------------------------------
__global__ __launch_bounds__(1024) void wo_kernel(
    const float* __restrict__ attn_s, const float* __restrict__ Wo,
    const float* __restrict__ bo, float* __restrict__ postx /* [1024][64] */)
{
    const int tid  = threadIdx.x;
    const int wv   = __builtin_amdgcn_readfirstlane(tid >> 6);
    const int lane = tid & 63;
    const int c0   = blockIdx.x * 8;
    const int k0   = wv * 64;

    float acc[8];
    #pragma unroll
    for (int j = 0; j < 8; ++j) acc[j] = 0.f;

    for (int k = 0; k < 64; ++k) {
        float sv = attn_s[(k0 + k) * 64 + lane];
        const float4* wr = (const float4*)(Wo + (size_t)(k0 + k) * 1024 + c0);
        float4 w0 = wr[0], w1 = wr[1];
        acc[0] = fmaf(sv, w0.x, acc[0]); acc[1] = fmaf(sv, w0.y, acc[1]);
        acc[2] = fmaf(sv, w0.z, acc[2]); acc[3] = fmaf(sv, w0.w, acc[3]);
        acc[4] = fmaf(sv, w1.x, acc[4]); acc[5] = fmaf(sv, w1.y, acc[5]);
        acc[6] = fmaf(sv, w1.z, acc[6]); acc[7] = fmaf(sv, w1.w, acc[7]);
    }

    __shared__ float red[16][8][64];
    #pragma unroll
    for (int j = 0; j < 8; ++j) red[wv][j][lane] = acc[j];
    __syncthreads();

    if (tid < 512) {
        const int j = tid >> 6, b = tid & 63;
        float s = 0.f;
        #pragma unroll
        for (int w = 0; w < 16; ++w) s += red[w][j][b];
        postx[(c0 + j) * 64 + b] = s + bo[c0 + j];
    }
}

// ---------------------------------------------------------------------------
// Kernel 5: dual LayerNorm (row-major proj reads, verified)
// ---------------------------------------------------------------------------
__global__ __launch_bounds__(256) void ln_kernel(
    const float* __restrict__ seq, const float* __restrict__ projRM,
    const float* __restrict__ postx, const float* __restrict__ gamma,
    const float* __restrict__ beta, float* __restrict__ out)
{
    const int b   = blockIdx.x;
    const int tid = threadIdx.x;
    float x1[4], x2[4];
    float s1 = 0.f, q1 = 0.f, s2 = 0.f, q2 = 0.f;

    #pragma unroll
    for (int i = 0; i < 4; ++i) {
        int c = tid + i * 256;
        float px = postx[c * 64 + b];
        float sv = seq[b * HID + c];
        float cd = projRM[(size_t)b * 4096 + 3072 + c];
        float a = sv + px, d = px + cd;
        x1[i] = a; x2[i] = d;
        s1 += a; q1 += a * a; s2 += d; q2 += d * d;
    }
    #pragma unroll
    for (int m = 1; m < 64; m <<= 1) {
        s1 += __shfl_xor(s1, m); q1 += __shfl_xor(q1, m);
        s2 += __shfl_xor(s2, m); q2 += __shfl_xor(q2, m);
    }
    __shared__ float rsm[4][4];
    const int wv = tid >> 6, lane = tid & 63;
    if (lane == 0) { rsm[wv][0] = s1; rsm[wv][1] = q1; rsm[wv][2] = s2; rsm[wv][3] = q2; }
    __syncthreads();

    float S1 = rsm[0][0] + rsm[1][0] + rsm[2][0] + rsm[3][0];
    float Q1 = rsm[0][1] + rsm[1][1] + rsm[2][1] + rsm[3][1];
    float S2 = rsm[0][2] + rsm[1][2] + rsm[2][2] + rsm[3][2];
    float Q2 = rsm[0][3] + rsm[1][3] + rsm[2][3] + rsm[3][3];

    const float inv = 1.f / 1024.f;
    float mu1 = S1 * inv, v1 = Q1 * inv - mu1 * mu1;
    float mu2 = S2 * inv, v2 = Q2 * inv - mu2 * mu2;
    float r1 = rsqrtf(v1 + 1e-5f);
    float r2 = rsqrtf(v2 + 1e-5f);

    #pragma unroll
    for (int i = 0; i < 4; ++i) {
        int c = tid + i * 256;
        float g = gamma[c], be = beta[c];
        out[b * HID + c]            = (x1[i] - mu1) * r1 * g + be;   // seq_out
        out[NB * HID + b * HID + c] = (x2[i] - mu2) * r2 * g + be;   // candidate_out
    }
}

// ---------------------------------------------------------------------------
extern "C" void kernel_launch(void* const* d_in, const int* in_sizes, int n_in,
                              void* d_out, int out_size, void* d_ws, size_t ws_size,
                              hipStream_t stream) {
    const float* seq      = (const float*)d_in[0];
    const float* cand     = (const float*)d_in[1];
    const float* k_cache  = (const float*)d_in[2];
    const float* v_cache  = (const float*)d_in[3];
    const int*   seqlens  = (const int*)  d_in[4];
    const float* Wqkv     = (const float*)d_in[5];
    const float* bqkv     = (const float*)d_in[6];
    const float* Wc       = (const float*)d_in[7];
    const float* bcv      = (const float*)d_in[8];
    const float* Wo       = (const float*)d_in[9];
    const float* bo       = (const float*)d_in[10];
    const float* gamma    = (const float*)d_in[11];
    const float* beta     = (const float*)d_in[12];
    float* out = (float*)d_out;

    float* ws      = (float*)d_ws;
    float* projRM  = ws;                          // [64][4096]      = 262144 f
    float* attn    = projRM + 64 * 4096;          // [1024][64]      =  65536 f
    float* postx   = attn   + 1024 * 64;          // [1024][64]      =  65536 f
    float* part    = postx  + 1024 * 64;          // [8*1024][PS]    = 557056 f
    float* partial = part   + NCH * 1024 * PS;    // [16][64][4096]  = 4194304 f (16 MB)

    proj1_kernel     <<<512, 256, 0, stream>>>(seq, cand, Wqkv, Wc, partial);
    proj2_kernel     <<<256, 1024, 0, stream>>>(partial, bqkv, bcv, projRM);
    attn_part_kernel <<<NCH * 1024, 256, 0, stream>>>(projRM, k_cache, v_cache, seqlens, part);
    attn_merge_kernel<<<NB * NHEAD, 64, 0, stream>>>(part, seqlens, attn);
    wo_kernel        <<<128, 1024, 0, stream>>>(attn, Wo, bo, postx);
    ln_kernel        <<<NB, 256, 0, stream>>>(seq, projRM, postx, gamma, beta, out);
}